// Round 3
// baseline (158.449 us; speedup 1.0000x reference)
//
#include <hip/hip_runtime.h>

// Problem constants (fixed by reference)
#define D_DIRS 1024
#define P_PTS  256
#define R_RANK 64
#define K_SUB  1024

typedef float v4f __attribute__((ext_vector_type(4)));

// Workspace layout in floats:
//   a[D][R]        @ 0        (65536)
//   b[D][R]        @ 65536    (65536)
//   Mpart[32][4096]@ 131072   (131072) -- per-block partial M, no atomics.
// Total 1 MiB (workspace is >=256 MiB per the harness poison fill).
#define WS_A 0
#define WS_B (D_DIRS * R_RANK)
#define WS_MP (2 * D_DIRS * R_RANK)
#define NB_B 32
#define DCHUNK (D_DIRS / NB_B) // 32

__device__ __forceinline__ v4f ntload(const v4f* __restrict__ p) {
    return __builtin_nontemporal_load(p);
}

__device__ __forceinline__ v4f shfl_xor_v4(v4f v, int m) {
    v4f r;
    r.x = __shfl_xor(v.x, m);
    r.y = __shfl_xor(v.y, m);
    r.z = __shfl_xor(v.z, m);
    r.w = __shfl_xor(v.w, m);
    return r;
}

// ---------------------------------------------------------------------------
// Kernel 1: p-reduction.  a[d,r] = sum_p atten[d,p,r]; b likewise.
// R9: reverted verbatim to the R5/R0 proven structure (33 us measured,
// 4.1 TB/s — the best of 8 structural variants across two sessions).
// Lessons locked in: (a) occupancy doubling was NEUTRAL (R7) — not
// latency-bound; (b) dropping nt REGRESSED to 44 us (R8): plain loads let
// the compiler collapse the 2-deep pipeline (VGPR 150->36) and the cached
// path contends with the harness's dirty fill lines (FETCH halved but
// 1.5 TB/s HBM). ~4.1 TB/s is treated as this part's streaming-read
// ceiling. Msum zero-init is GONE (k2 no longer uses atomics).
// ---------------------------------------------------------------------------
__global__ __launch_bounds__(512) void k_reduce_p(const float* __restrict__ atten,
                                                  const float* __restrict__ rad,
                                                  float* __restrict__ ws) {
    const int t    = threadIdx.x;
    const int wave = t >> 6;
    const int lane = t & 63;
    const int d    = blockIdx.x * 4 + (wave >> 1);
    const int half = wave & 1;
    const int r4g  = lane & 7;
    const int pr   = lane >> 3;

    const int base = pr * 16 + half * 8 + r4g; // within-slab float4 offset, c=0
    const v4f* A4 = (const v4f*)atten + (size_t)d * 4096 + base;
    const v4f* B4 = (const v4f*)rad   + (size_t)d * 4096 + base;

    v4f pa[8], pb[8], na[8], nb[8];
#pragma unroll
    for (int j = 0; j < 8; ++j) pa[j] = ntload(A4 + j * 128);
#pragma unroll
    for (int j = 0; j < 8; ++j) pb[j] = ntload(B4 + j * 128);

    v4f acc_a = {0.f, 0.f, 0.f, 0.f};
    v4f acc_b = {0.f, 0.f, 0.f, 0.f};

#pragma unroll
    for (int mc = 0; mc < 4; ++mc) {
        if (mc < 3) {
            const int off = (mc + 1) * 8 * 128;
#pragma unroll
            for (int j = 0; j < 8; ++j) na[j] = ntload(A4 + off + j * 128);
#pragma unroll
            for (int j = 0; j < 8; ++j) nb[j] = ntload(B4 + off + j * 128);
        }
        acc_a = acc_a + (((pa[0] + pa[1]) + (pa[2] + pa[3])) +
                         ((pa[4] + pa[5]) + (pa[6] + pa[7])));
        acc_b = acc_b + (((pb[0] + pb[1]) + (pb[2] + pb[3])) +
                         ((pb[4] + pb[5]) + (pb[6] + pb[7])));
#pragma unroll
        for (int j = 0; j < 8; ++j) { pa[j] = na[j]; pb[j] = nb[j]; }
    }

    // Reduce across pr (lanes sharing r4g): xor 8, 16, 32. No barriers.
    acc_a = acc_a + shfl_xor_v4(acc_a, 8);
    acc_a = acc_a + shfl_xor_v4(acc_a, 16);
    acc_a = acc_a + shfl_xor_v4(acc_a, 32);
    acc_b = acc_b + shfl_xor_v4(acc_b, 8);
    acc_b = acc_b + shfl_xor_v4(acc_b, 16);
    acc_b = acc_b + shfl_xor_v4(acc_b, 32);

    if (pr == 0) { // lanes 0..7
        ((v4f*)(ws + WS_A))[d * 16 + half * 8 + r4g] = acc_a;
        ((v4f*)(ws + WS_B))[d * 16 + half * 8 + r4g] = acc_b;
    }
}

// ---------------------------------------------------------------------------
// Kernel 2: M accumulation.  Block bb covers d in [bb*32, bb*32+32); computes
// its 64x64 partial in registers then writes it to its PRIVATE slice
// Mpart[bb] with plain coalesced stores. R9 change: no atomics, no
// zero-init dependency, no 32-way contention; k3 sums the 32 partials.
// ---------------------------------------------------------------------------
__global__ __launch_bounds__(256) void k_partial_m(float* __restrict__ ws) {
    const int bb = blockIdx.x;
    const int t  = threadIdx.x;

    __shared__ float sa[DCHUNK * R_RANK]; // 8 KiB
    __shared__ float sb[DCHUNK * R_RANK]; // 8 KiB

    const float4* a4 = (const float4*)(ws + WS_A) + bb * (DCHUNK * R_RANK / 4);
    const float4* b4 = (const float4*)(ws + WS_B) + bb * (DCHUNK * R_RANK / 4);
    float4* sa4 = (float4*)sa;
    float4* sb4 = (float4*)sb;
    sa4[t]       = a4[t];
    sa4[t + 256] = a4[t + 256];
    sb4[t]       = b4[t];
    sb4[t + 256] = b4[t + 256];
    __syncthreads();

    const int c  = t & 63;
    const int wg = t >> 6;

    float acc[16];
#pragma unroll
    for (int i = 0; i < 16; ++i) acc[i] = 0.f;

    for (int dd = 0; dd < DCHUNK; ++dd) {
        const float bv = sb[dd * 64 + c];
        const float4* ar = (const float4*)&sa[dd * 64 + wg * 16];
        const float4 a0 = ar[0], a1 = ar[1], a2 = ar[2], a3 = ar[3];
        acc[0]  += a0.x * bv; acc[1]  += a0.y * bv; acc[2]  += a0.z * bv; acc[3]  += a0.w * bv;
        acc[4]  += a1.x * bv; acc[5]  += a1.y * bv; acc[6]  += a1.z * bv; acc[7]  += a1.w * bv;
        acc[8]  += a2.x * bv; acc[9]  += a2.y * bv; acc[10] += a2.z * bv; acc[11] += a2.w * bv;
        acc[12] += a3.x * bv; acc[13] += a3.y * bv; acc[14] += a3.z * bv; acc[15] += a3.w * bv;
    }

    float* Mp = ws + WS_MP + bb * 4096;
#pragma unroll
    for (int i = 0; i < 16; ++i)
        Mp[(wg * 16 + i) * 64 + c] = acc[i];
}

// ---------------------------------------------------------------------------
// Kernel 3: csi[k] = (1/D) F[k] M F[k]^T, where M = sum of 32 partials.
// 16 blocks x 256 threads; block bb owns k in [bb*64, bb*64+64).
// R9 change: Ms staging sums Mpart[0..31] (128 float4 L2 loads/thread,
// independent across the 4 i-slots — latency-hidden).
// Fs padded stride 65 -> conflict-free; Ms reads are wave-uniform broadcasts.
// ---------------------------------------------------------------------------
__global__ __launch_bounds__(256) void k_csi(const float* __restrict__ ws,
                                             const float* __restrict__ freq,
                                             float* __restrict__ out) {
    const int bb = blockIdx.x;
    const int t  = threadIdx.x;

    __shared__ float Ms[64 * 68];   // ~17 KiB
    __shared__ float Fs[64 * 65];   // ~16.6 KiB
    __shared__ float red[4][64];

    const float4* MP4 = (const float4*)(ws + WS_MP);
#pragma unroll
    for (int i = 0; i < 4; ++i) {
        const int idx4 = i * 256 + t;
        float4 s = {0.f, 0.f, 0.f, 0.f};
#pragma unroll 4
        for (int p = 0; p < 32; ++p) {
            const float4 v = MP4[p * 1024 + idx4];
            s.x += v.x; s.y += v.y; s.z += v.z; s.w += v.w;
        }
        const int r = idx4 >> 4, c4 = idx4 & 15;
        *(float4*)&Ms[r * 68 + c4 * 4] = s;
    }

    const float4* F4 = (const float4*)freq + bb * 1024;
#pragma unroll
    for (int i = 0; i < 4; ++i) {
        const int idx4 = i * 256 + t;
        const float4 v = F4[idx4];
        const int row = idx4 >> 4, c4 = idx4 & 15;
        Fs[row * 65 + c4 * 4 + 0] = v.x;
        Fs[row * 65 + c4 * 4 + 1] = v.y;
        Fs[row * 65 + c4 * 4 + 2] = v.z;
        Fs[row * 65 + c4 * 4 + 3] = v.w;
    }
    __syncthreads();

    const int kl = t & 63;
    const int jg = t >> 6;

    float h[16];
#pragma unroll
    for (int j = 0; j < 16; ++j) h[j] = 0.f;

    for (int r = 0; r < 64; ++r) {
        const float fv = Fs[kl * 65 + r];
        const float4* mr = (const float4*)&Ms[r * 68 + jg * 16];
        const float4 m0 = mr[0], m1 = mr[1], m2 = mr[2], m3 = mr[3];
        h[0]  += fv * m0.x; h[1]  += fv * m0.y; h[2]  += fv * m0.z; h[3]  += fv * m0.w;
        h[4]  += fv * m1.x; h[5]  += fv * m1.y; h[6]  += fv * m1.z; h[7]  += fv * m1.w;
        h[8]  += fv * m2.x; h[9]  += fv * m2.y; h[10] += fv * m2.z; h[11] += fv * m2.w;
        h[12] += fv * m3.x; h[13] += fv * m3.y; h[14] += fv * m3.z; h[15] += fv * m3.w;
    }

    float part = 0.f;
#pragma unroll
    for (int j = 0; j < 16; ++j) part += h[j] * Fs[kl * 65 + jg * 16 + j];

    red[jg][kl] = part;
    __syncthreads();
    if (t < 64) {
        out[bb * 64 + t] =
            (red[0][t] + red[1][t] + red[2][t] + red[3][t]) * (1.0f / (float)D_DIRS);
    }
}

extern "C" void kernel_launch(void* const* d_in, const int* in_sizes, int n_in,
                              void* d_out, int out_size, void* d_ws, size_t ws_size,
                              hipStream_t stream) {
    const float* atten = (const float*)d_in[0]; // (D,P,R)
    const float* rad   = (const float*)d_in[1]; // (D,P,R)
    const float* freq  = (const float*)d_in[2]; // (K,R)
    float* out = (float*)d_out;                 // (K,)
    float* ws  = (float*)d_ws;                  // needs 1 MiB

    k_reduce_p<<<D_DIRS / 4, 512, 0, stream>>>(atten, rad, ws);
    k_partial_m<<<NB_B, 256, 0, stream>>>(ws);
    k_csi<<<16, 256, 0, stream>>>(ws, freq, out);
}

// Round 4
// 156.519 us; speedup vs baseline: 1.0123x; 1.0123x over previous
//
#include <hip/hip_runtime.h>

// Problem constants (fixed by reference)
#define D_DIRS 1024
#define P_PTS  256
#define R_RANK 64
#define K_SUB  1024

typedef float v4f __attribute__((ext_vector_type(4)));

// Workspace layout in floats:
//   a[D][R]      @ 0        (65536)
//   b[D][R]      @ 65536    (65536)
//   Msum[64][64] @ 131072   (4096)   -- zeroed by k1 block 0, atomically
//                                       accumulated by k_partial_m.
#define WS_A 0
#define WS_B (D_DIRS * R_RANK)
#define WS_MSUM (2 * D_DIRS * R_RANK)
#define NB_B 32
#define DCHUNK (D_DIRS / NB_B) // 32

__device__ __forceinline__ v4f shfl_xor_v4(v4f v, int m) {
    v4f r;
    r.x = __shfl_xor(v.x, m);
    r.y = __shfl_xor(v.y, m);
    r.z = __shfl_xor(v.z, m);
    r.w = __shfl_xor(v.w, m);
    return r;
}

// Plain (cache-allocating) 16B load the compiler cannot collapse or sink:
// R2 showed plain C loads get 50% LLC hits (FETCH 134->67 MB) but the
// compiler destroyed the prefetch pipeline (VGPR 150->36, latency-bound).
// Inline asm preserves issue order and register residency; waitcnt is
// managed manually below.
__device__ __forceinline__ v4f gload(const v4f* __restrict__ p) {
    v4f r;
    asm volatile("global_load_dwordx4 %0, %1, off"
                 : "=v"(r) : "v"(p) : "memory");
    return r;
}

#define WAIT_VM16() asm volatile("s_waitcnt vmcnt(16)" ::: "memory")
#define WAIT_VM0()  asm volatile("s_waitcnt vmcnt(0)"  ::: "memory")

// ---------------------------------------------------------------------------
// Kernel 1: p-reduction.  a[d,r] = sum_p atten[d,p,r]; b likewise.
// R10: R0/R5 wave-private structure (512 thr, wave owns (d, half-slab),
// 8-load chunks, 2-deep, shfl_xor reduce, no barriers) with ONE change:
// loads are plain cached reads via inline asm instead of nontemporal.
//   - nt bypassed LLC: full 134 MB HBM fetch, capped ~4.1 TB/s (R0).
//   - plain C loads: 50% LLC hits but compiler collapsed the pipeline (R2).
//   - asm loads + counted s_waitcnt vmcnt(16) per chunk (never 0 in-loop)
//     + sched_barrier(0) after each wait (VALU hoists past asm waitcnts
//     otherwise) keep 16-32 loads in flight AND allocate in LLC.
// Per-chunk buffers are statically indexed (bufA[mc][j], fully unrolled) so
// the na->pa copies vanish via register renaming.
// Block 0 zeroes Msum first and drains with vmcnt(0) so the counted waits
// in the pipeline stay exact (stores also count in vmcnt).
// ---------------------------------------------------------------------------
__global__ __launch_bounds__(512) void k_reduce_p(const float* __restrict__ atten,
                                                  const float* __restrict__ rad,
                                                  float* __restrict__ ws) {
    const int t    = threadIdx.x;
    const int wave = t >> 6;
    const int lane = t & 63;
    const int d    = blockIdx.x * 4 + (wave >> 1);
    const int half = wave & 1;
    const int r4g  = lane & 7;
    const int pr   = lane >> 3;

    if (blockIdx.x == 0) { // zero Msum: 512 threads x 2 float4 = 4096 floats
        v4f z = {0.f, 0.f, 0.f, 0.f};
        ((v4f*)(ws + WS_MSUM))[t]       = z;
        ((v4f*)(ws + WS_MSUM))[t + 512] = z;
        WAIT_VM0(); // drain stores so pipeline vmcnt counts stay exact
    }

    const int base = pr * 16 + half * 8 + r4g; // within-slab float4 offset
    const v4f* A4 = (const v4f*)atten + (size_t)d * 4096 + base;
    const v4f* B4 = (const v4f*)rad   + (size_t)d * 4096 + base;

    v4f bufA[4][8], bufB[4][8]; // statically indexed only (fully unrolled)
    v4f acc_a = {0.f, 0.f, 0.f, 0.f};
    v4f acc_b = {0.f, 0.f, 0.f, 0.f};

    // Prologue: issue chunk 0 (16 loads).
#pragma unroll
    for (int j = 0; j < 8; ++j) bufA[0][j] = gload(A4 + j * 128);
#pragma unroll
    for (int j = 0; j < 8; ++j) bufB[0][j] = gload(B4 + j * 128);

#pragma unroll
    for (int mc = 0; mc < 4; ++mc) {
        if (mc < 3) {
            const int off = (mc + 1) * 1024; // chunk stride in float4
#pragma unroll
            for (int j = 0; j < 8; ++j) bufA[mc + 1][j] = gload(A4 + off + j * 128);
#pragma unroll
            for (int j = 0; j < 8; ++j) bufB[mc + 1][j] = gload(B4 + off + j * 128);
            WAIT_VM16(); // chunk mc complete; chunk mc+1 stays in flight
        } else {
            WAIT_VM0();  // final chunk
        }
        __builtin_amdgcn_sched_barrier(0);
        acc_a = acc_a + (((bufA[mc][0] + bufA[mc][1]) + (bufA[mc][2] + bufA[mc][3])) +
                         ((bufA[mc][4] + bufA[mc][5]) + (bufA[mc][6] + bufA[mc][7])));
        acc_b = acc_b + (((bufB[mc][0] + bufB[mc][1]) + (bufB[mc][2] + bufB[mc][3])) +
                         ((bufB[mc][4] + bufB[mc][5]) + (bufB[mc][6] + bufB[mc][7])));
    }

    // Reduce across pr (lanes sharing r4g): xor 8, 16, 32. No barriers.
    acc_a = acc_a + shfl_xor_v4(acc_a, 8);
    acc_a = acc_a + shfl_xor_v4(acc_a, 16);
    acc_a = acc_a + shfl_xor_v4(acc_a, 32);
    acc_b = acc_b + shfl_xor_v4(acc_b, 8);
    acc_b = acc_b + shfl_xor_v4(acc_b, 16);
    acc_b = acc_b + shfl_xor_v4(acc_b, 32);

    if (pr == 0) { // lanes 0..7
        ((v4f*)(ws + WS_A))[d * 16 + half * 8 + r4g] = acc_a;
        ((v4f*)(ws + WS_B))[d * 16 + half * 8 + r4g] = acc_b;
    }
}

// ---------------------------------------------------------------------------
// Kernel 2: M accumulation.  Block bb covers d in [bb*32, bb*32+32); computes
// its 64x64 partial in registers then atomicAdds into Msum. R0-proven form
// restored: R9's private-partials + k3 re-reduce variant cost +11.5 us
// (under-occupied k3 summing 32 partials at L2 latency); the 131K atomics
// (32-way contention per address) are cheaper. fp32 reassociation is well
// inside the absmax threshold (1.0 vs 37.8).
// ---------------------------------------------------------------------------
__global__ __launch_bounds__(256) void k_partial_m(float* __restrict__ ws) {
    const int bb = blockIdx.x;
    const int t  = threadIdx.x;

    __shared__ float sa[DCHUNK * R_RANK]; // 8 KiB
    __shared__ float sb[DCHUNK * R_RANK]; // 8 KiB

    const float4* a4 = (const float4*)(ws + WS_A) + bb * (DCHUNK * R_RANK / 4);
    const float4* b4 = (const float4*)(ws + WS_B) + bb * (DCHUNK * R_RANK / 4);
    float4* sa4 = (float4*)sa;
    float4* sb4 = (float4*)sb;
    sa4[t]       = a4[t];
    sa4[t + 256] = a4[t + 256];
    sb4[t]       = b4[t];
    sb4[t + 256] = b4[t + 256];
    __syncthreads();

    const int c  = t & 63;
    const int wg = t >> 6;

    float acc[16];
#pragma unroll
    for (int i = 0; i < 16; ++i) acc[i] = 0.f;

    for (int dd = 0; dd < DCHUNK; ++dd) {
        const float bv = sb[dd * 64 + c];
        const float4* ar = (const float4*)&sa[dd * 64 + wg * 16];
        const float4 a0 = ar[0], a1 = ar[1], a2 = ar[2], a3 = ar[3];
        acc[0]  += a0.x * bv; acc[1]  += a0.y * bv; acc[2]  += a0.z * bv; acc[3]  += a0.w * bv;
        acc[4]  += a1.x * bv; acc[5]  += a1.y * bv; acc[6]  += a1.z * bv; acc[7]  += a1.w * bv;
        acc[8]  += a2.x * bv; acc[9]  += a2.y * bv; acc[10] += a2.z * bv; acc[11] += a2.w * bv;
        acc[12] += a3.x * bv; acc[13] += a3.y * bv; acc[14] += a3.z * bv; acc[15] += a3.w * bv;
    }

    float* Msum = ws + WS_MSUM;
#pragma unroll
    for (int i = 0; i < 16; ++i)
        atomicAdd(&Msum[(wg * 16 + i) * 64 + c], acc[i]);
}

// ---------------------------------------------------------------------------
// Kernel 3: csi[k] = (1/D) F[k] Msum F[k]^T.
// 16 blocks x 256 threads; block bb owns k in [bb*64, bb*64+64).
// Fs padded stride 65 -> conflict-free; Ms reads are wave-uniform broadcasts.
// ---------------------------------------------------------------------------
__global__ __launch_bounds__(256) void k_csi(const float* __restrict__ ws,
                                             const float* __restrict__ freq,
                                             float* __restrict__ out) {
    const int bb = blockIdx.x;
    const int t  = threadIdx.x;

    __shared__ float Ms[64 * 68];   // ~17 KiB
    __shared__ float Fs[64 * 65];   // ~16.6 KiB
    __shared__ float red[4][64];

    const float4* M4 = (const float4*)(ws + WS_MSUM);
#pragma unroll
    for (int i = 0; i < 4; ++i) {
        const int idx4 = i * 256 + t;
        const float4 s = M4[idx4];
        const int r = idx4 >> 4, c4 = idx4 & 15;
        *(float4*)&Ms[r * 68 + c4 * 4] = s;
    }

    const float4* F4 = (const float4*)freq + bb * 1024;
#pragma unroll
    for (int i = 0; i < 4; ++i) {
        const int idx4 = i * 256 + t;
        const float4 v = F4[idx4];
        const int row = idx4 >> 4, c4 = idx4 & 15;
        Fs[row * 65 + c4 * 4 + 0] = v.x;
        Fs[row * 65 + c4 * 4 + 1] = v.y;
        Fs[row * 65 + c4 * 4 + 2] = v.z;
        Fs[row * 65 + c4 * 4 + 3] = v.w;
    }
    __syncthreads();

    const int kl = t & 63;
    const int jg = t >> 6;

    float h[16];
#pragma unroll
    for (int j = 0; j < 16; ++j) h[j] = 0.f;

    for (int r = 0; r < 64; ++r) {
        const float fv = Fs[kl * 65 + r];
        const float4* mr = (const float4*)&Ms[r * 68 + jg * 16];
        const float4 m0 = mr[0], m1 = mr[1], m2 = mr[2], m3 = mr[3];
        h[0]  += fv * m0.x; h[1]  += fv * m0.y; h[2]  += fv * m0.z; h[3]  += fv * m0.w;
        h[4]  += fv * m1.x; h[5]  += fv * m1.y; h[6]  += fv * m1.z; h[7]  += fv * m1.w;
        h[8]  += fv * m2.x; h[9]  += fv * m2.y; h[10] += fv * m2.z; h[11] += fv * m2.w;
        h[12] += fv * m3.x; h[13] += fv * m3.y; h[14] += fv * m3.z; h[15] += fv * m3.w;
    }

    float part = 0.f;
#pragma unroll
    for (int j = 0; j < 16; ++j) part += h[j] * Fs[kl * 65 + jg * 16 + j];

    red[jg][kl] = part;
    __syncthreads();
    if (t < 64) {
        out[bb * 64 + t] =
            (red[0][t] + red[1][t] + red[2][t] + red[3][t]) * (1.0f / (float)D_DIRS);
    }
}

extern "C" void kernel_launch(void* const* d_in, const int* in_sizes, int n_in,
                              void* d_out, int out_size, void* d_ws, size_t ws_size,
                              hipStream_t stream) {
    const float* atten = (const float*)d_in[0]; // (D,P,R)
    const float* rad   = (const float*)d_in[1]; // (D,P,R)
    const float* freq  = (const float*)d_in[2]; // (K,R)
    float* out = (float*)d_out;                 // (K,)
    float* ws  = (float*)d_ws;                  // needs 528 KiB

    k_reduce_p<<<D_DIRS / 4, 512, 0, stream>>>(atten, rad, ws);
    k_partial_m<<<NB_B, 256, 0, stream>>>(ws);
    k_csi<<<16, 256, 0, stream>>>(ws, freq, out);
}